// Round 4
// baseline (301.903 us; speedup 1.0000x reference)
//
#include <hip/hip_runtime.h>
#include <math.h>

#define NPIX 9216        // 96*96
#define SCALE 0.17677669529663687f
#define LOG2E 1.4426950408889634f

typedef __attribute__((ext_vector_type(8))) short bh8;   // 8 x bf16 (4 VGPRs)
typedef __attribute__((ext_vector_type(4))) float f4;    // MFMA C/D

__device__ __forceinline__ unsigned short f2bf(float f) {
    unsigned u = __float_as_uint(f);
    u += 0x7fff + ((u >> 16) & 1);          // RNE
    return (unsigned short)(u >> 16);
}
__device__ __forceinline__ void gload_lds16(const void* g, void* l) {
    __builtin_amdgcn_global_load_lds(
        (const __attribute__((address_space(1))) unsigned int*)g,
        (__attribute__((address_space(3))) unsigned int*)l, 16, 0, 0);
}

// ---------------------------------------------------------------------------
// Kernel 0: W (q;kv) fp32 -> bf16 [768][256]; blocks 768+: hrel/wrel fp32 ->
// bf16 relb[2][32][32], pre-scaled by LOG2E, rows >=27 zeroed.
// ---------------------------------------------------------------------------
__global__ void wconv_kernel(const float* __restrict__ qw, const float* __restrict__ kvw,
                             const float* __restrict__ hrel, const float* __restrict__ wrel,
                             unsigned short* __restrict__ Wb,
                             unsigned short* __restrict__ relb) {
    int bid = blockIdx.x, tid = threadIdx.x;
    if (bid < 768) {
        float v = (bid < 256) ? qw[bid * 256 + tid] : kvw[(bid - 256) * 256 + tid];
        Wb[bid * 256 + tid] = f2bf(v);
    } else {
        int e = (bid - 768) * 256 + tid;      // [0, 2048)
        int half = e >> 10, r = (e >> 5) & 31, d = e & 31;
        float v = 0.0f;
        if (r < 27) v = (half ? wrel : hrel)[r * 32 + d] * LOG2E;
        relb[half * 1024 + r * 32 + d] = f2bf(v);
    }
}

// ---------------------------------------------------------------------------
// Kernel 1: x[b][256][9216] fp32 -> xt[b][9216][256] bf16 (transpose+convert)
// ---------------------------------------------------------------------------
__global__ __launch_bounds__(256) void xtrans_kernel(const float* __restrict__ x,
                                                     unsigned short* __restrict__ xt) {
    int b = blockIdx.z;
    int p0 = blockIdx.x * 128, c0 = blockIdx.y * 128;
    int tid = threadIdx.x;
    __shared__ __align__(16) unsigned short ts[128 * 136];   // [pix][ch], pitch 136
    const float* xb = x + (size_t)b * 256 * NPIX;
    #pragma unroll
    for (int it = 0; it < 16; ++it) {
        int e = it * 256 + tid;
        int ch = e >> 5, p4 = (e & 31) * 4;
        float4 v = *(const float4*)(xb + (size_t)(c0 + ch) * NPIX + p0 + p4);
        ts[(p4 + 0) * 136 + ch] = f2bf(v.x);
        ts[(p4 + 1) * 136 + ch] = f2bf(v.y);
        ts[(p4 + 2) * 136 + ch] = f2bf(v.z);
        ts[(p4 + 3) * 136 + ch] = f2bf(v.w);
    }
    __syncthreads();
    unsigned short* xtb = xt + (size_t)b * NPIX * 256;
    #pragma unroll
    for (int it = 0; it < 8; ++it) {
        int e = it * 256 + tid;
        int p = e >> 4, ck = (e & 15) * 8;
        *(int4*)(xtb + (size_t)(p0 + p) * 256 + c0 + ck) = *(const int4*)&ts[p * 136 + ck];
    }
}

// ---------------------------------------------------------------------------
// Kernel 2: projection GEMM, bf16 MFMA (unchanged from round 1).
// ---------------------------------------------------------------------------
__global__ __launch_bounds__(256) void proj_kernel(const unsigned short* __restrict__ xt,
                                                   const unsigned short* __restrict__ Wb,
                                                   unsigned short* __restrict__ qb,
                                                   unsigned short* __restrict__ kvb) {
    int flat = blockIdx.x + 72 * (blockIdx.y + 6 * blockIdx.z);   // 0..3455, x fastest
    int w = (flat & 7) * 432 + (flat >> 3);    // per-XCD contiguous slot run
    int n0 = (w % 6) * 128;                    // out-ch block (fastest within XCD)
    int m0 = ((w / 6) % 72) * 128;             // pix block
    int b  = w / 432;                          // == xcd: one batch per XCD
    int tid = threadIdx.x, lane = tid & 63, wave = tid >> 6;
    int ll = lane & 15;
    __shared__ __align__(16) char smem[34816];
    char* As = smem;             // [128 pix][64 k] bf16, rows 128 B
    char* Bs = smem + 16384;     // [128 ch ][64 k] bf16
    const unsigned short* xtb = xt + (size_t)b * NPIX * 256;

    f4 acc[4][4] = {};
    int wm = (wave & 1) * 64, wn = (wave >> 1) * 64;

    for (int k0 = 0; k0 < 256; k0 += 64) {
        __syncthreads();
        #pragma unroll
        for (int i = 0; i < 4; ++i) {
            int c = wave * 4 + i;   // chunk: 8 rows x 128B = 1 KB
            gload_lds16(xtb + (size_t)(m0 + c * 8 + (lane >> 3)) * 256 + k0 + (lane & 7) * 8,
                        As + c * 1024);
            gload_lds16(Wb + (size_t)(n0 + c * 8 + (lane >> 3)) * 256 + k0 + (lane & 7) * 8,
                        Bs + c * 1024);
        }
        __syncthreads();
        #pragma unroll
        for (int ks = 0; ks < 2; ++ks) {
            bh8 af[4], bf[4];
            #pragma unroll
            for (int i = 0; i < 4; ++i)
                af[i] = *(const bh8*)(As + (wm + i * 16 + ll) * 128 + ks * 64 + (lane >> 4) * 16);
            #pragma unroll
            for (int j = 0; j < 4; ++j)
                bf[j] = *(const bh8*)(Bs + (wn + j * 16 + ll) * 128 + ks * 64 + (lane >> 4) * 16);
            #pragma unroll
            for (int i = 0; i < 4; ++i)
                #pragma unroll
                for (int j = 0; j < 4; ++j)
                    acc[i][j] = __builtin_amdgcn_mfma_f32_16x16x32_bf16(af[i], bf[j], acc[i][j], 0, 0, 0);
        }
    }

    // ---- epilogue: acc -> LDS bf16 tile [128][136] -> coalesced int4 stores
    __syncthreads();
    unsigned short* ts = (unsigned short*)smem;
    int q4 = (lane >> 4) * 4;
    #pragma unroll
    for (int i = 0; i < 4; ++i) {
        #pragma unroll
        for (int j = 0; j < 4; ++j) {
            int ch = wn + j * 16 + ll;
            #pragma unroll
            for (int r = 0; r < 4; ++r)
                ts[(wm + i * 16 + q4 + r) * 136 + ch] = f2bf(acc[i][j][r]);
        }
    }
    __syncthreads();
    bool isQ = (n0 < 256);
    #pragma unroll
    for (int it = 0; it < 8; ++it) {
        int e = it * 256 + tid;
        int pixl = e >> 4, ck = (e & 15) * 8;
        int4 v = *(const int4*)&ts[pixl * 136 + ck];
        int pix = m0 + pixl, ch = n0 + ck;
        if (isQ) {
            int head = ch >> 5, d = ch & 31;
            *(int4*)&qb[((size_t)(b * 8 + head) * NPIX + pix) * 32 + d] = v;
        } else {
            int c = ch - 256, head = c >> 6, dv = c & 63;
            *(int4*)&kvb[((size_t)(b * 8 + head) * NPIX + pix) * 64 + dv] = v;
        }
    }
}

// ---------------------------------------------------------------------------
// Kernel 3: halo attention (round-1 base, consolidated):
//   - K: direct global->MFMA B-fragments (predicated; Ks stage + S1 removed).
//     Zero fragments for pad/halo == reference zero-padding (S=0 cols stay
//     in the softmax denominator, matching ref).
//   - RhT/Rw wave-private inside the Ps strip -> single __syncthreads.
//   - Vt granule-swizzled staging + PV + epilogue identical to round-1.
// LDS map (45312 B, 3 blocks/CU):
//   [0,15360)          Vt[32][240] bf16, granule-XOR swizzled
//   strip w = 15360 + wave*7424, 7424 B each:
//     [0,2240)   RhTw[28][20] fp32   (dies at logits)
//     [2240,3712) Rww[16][23] fp32   (dies at logits)
//     [0,7424)   Ps[16][232] bf16    (overlays after logits; same wave only)
//   [45056,45312)      smR[64] fp32 row-sums
// ---------------------------------------------------------------------------
__global__ __launch_bounds__(256) void attn_kernel(const unsigned short* __restrict__ qbuf,
                                                   const unsigned short* __restrict__ kvbuf,
                                                   const unsigned short* __restrict__ relb,
                                                   float* __restrict__ out) {
    int flat = blockIdx.x + 144 * blockIdx.y;       // 0..9215, x fastest
    int w = (flat & 7) * 1152 + (flat >> 3);        // XCD gets 8 full bh planes
    int nbid = w % 144, bh = w / 144;
    int b = bh >> 3, head = bh & 7;
    int hb = nbid / 12, wblk = nbid % 12;
    int r0 = hb * 8, c0 = wblk * 8;
    int tid = threadIdx.x, lane = tid & 63, wave = tid >> 6;
    int ll = lane & 15, lq = lane >> 4;
    int m0 = wave * 16;

    __shared__ __align__(16) char smem[45312];
    unsigned short* Vt = (unsigned short*)smem;                 // [32][240]
    char* strip = smem + 15360 + wave * 7424;
    float*          RhTw = (float*)strip;                       // [28][20]
    float*          Rww  = (float*)(strip + 2240);              // [16][23]
    unsigned short* Ps   = (unsigned short*)strip;              // [16][232] overlay
    float*          smR  = (float*)(smem + 45056);

    const unsigned short* qb  = qbuf  + (size_t)bh * NPIX * 32;
    const unsigned short* kvb = kvbuf + (size_t)bh * NPIX * 64;

    // ---- Q fragment straight from global (A-operand layout)
    int qp0 = m0 + ll;
    int pixq = (r0 + (qp0 >> 3)) * 96 + c0 + (qp0 & 7);
    bh8 aq = *(const bh8*)&qb[(size_t)pixq * 32 + lq * 8];

    // ---- stage V transposed: Vt[d][granule-swizzled kp], pair-packed b32
    #pragma unroll
    for (int it = 0; it < 2; ++it) {
        int e = it * 256 + tid;
        int part = e >> 7, kp2 = e & 127;
        if (kp2 < 112) {
            int a = kp2 >> 3, b2 = (kp2 & 7) * 2;
            int gr = r0 + a - 3, gc = c0 + b2 - 3;
            int4 lo = {0, 0, 0, 0}, hi = {0, 0, 0, 0};
            bool rok = ((kp2 & 7) < 7) && ((unsigned)gr < 96u);
            if (rok && (unsigned)gc < 96u)
                lo = *(const int4*)&kvb[(size_t)(gr * 96 + gc) * 64 + 32 + part * 8];
            if (rok && (unsigned)(gc + 1) < 96u)
                hi = *(const int4*)&kvb[(size_t)(gr * 96 + gc + 1) * 64 + 32 + part * 8];
            int g = kp2 >> 2, kb = b2 & 7;
            const unsigned* lw = (const unsigned*)&lo;
            const unsigned* hw = (const unsigned*)&hi;
            #pragma unroll
            for (int jw = 0; jw < 4; ++jw) {
                unsigned l2 = lw[jw], h2 = hw[jw];
                unsigned v0 = (l2 & 0xffffu) | (h2 << 16);
                unsigned v1 = (l2 >> 16) | (h2 & 0xffff0000u);
                int d0 = part * 8 + jw * 2;
                int s0 = (((jw * 2) & 3) + part) & 3;
                int s1 = (((jw * 2 + 1) & 3) + part) & 3;
                *(unsigned*)&Vt[d0 * 240 + ((g ^ s0) * 8) + kb] = v0;
                *(unsigned*)&Vt[(d0 + 1) * 240 + ((g ^ s1) * 8) + kb] = v1;
            }
        }
    }

    // ---- rel dot-products via MFMA (wave-private rows; relb pre-scaled LOG2E)
    f4 zero4 = {0.f, 0.f, 0.f, 0.f};
    #pragma unroll
    for (int t = 0; t < 2; ++t) {
        int r = t * 16 + ll;
        bh8 hbv = *(const bh8*)&relb[(size_t)r * 32 + lq * 8];
        bh8 wbv = *(const bh8*)&relb[1024 + (size_t)r * 32 + lq * 8];
        f4 ch = __builtin_amdgcn_mfma_f32_16x16x32_bf16(aq, hbv, zero4, 0, 0, 0);
        f4 cw = __builtin_amdgcn_mfma_f32_16x16x32_bf16(aq, wbv, zero4, 0, 0, 0);
        if (r < 28) *(f4*)&RhTw[r * 20 + lq * 4] = ch;
        if (r >= 6 && r < 27) {
            #pragma unroll
            for (int rr = 0; rr < 4; ++rr)
                Rww[(lq * 4 + rr) * 23 + (r - 6)] = cw[rr];
        }
    }

    // ---- S = Q K^T, K fragments direct from global (zero rows == ref padding)
    int gcq = c0 + ll - 3;
    bool lane_ok = (ll < 14) && ((unsigned)gcq < 96u);
    const unsigned short* kcol = kvb + (size_t)gcq * 64 + lq * 8;
    f4 S[14];
    #pragma unroll
    for (int t = 0; t < 14; ++t) {
        int gr = r0 + t - 3;
        bh8 bk = {};
        if (lane_ok && (unsigned)gr < 96u)
            bk = *(const bh8*)(kcol + (size_t)gr * 96 * 64);
        S[t] = __builtin_amdgcn_mfma_f32_16x16x32_bf16(aq, bk, zero4, 0, 0, 0);
    }

    // ---- logits (log2 domain), exp2 without max-subtraction, row sums
    int row0 = m0 + lq * 4;
    int h = row0 >> 3;                             // quad-uniform
    bool valid = (ll < 14);
    float rw4[4];
    #pragma unroll
    for (int rr = 0; rr < 4; ++rr) {
        int row = row0 + rr;
        rw4[rr] = valid ? Rww[(lq * 4 + rr) * 23 + 7 + ll - (row & 7)] : -INFINITY;
    }
    const float SL = SCALE * LOG2E;
    float sm4[4] = {0.f, 0.f, 0.f, 0.f};
    #pragma unroll
    for (int t = 0; t < 14; ++t) {
        f4 rh = *(const f4*)&RhTw[(13 + t - h) * 20 + lq * 4];
        #pragma unroll
        for (int rr = 0; rr < 4; ++rr) {
            float lg = S[t][rr] * SL + rh[rr] + rw4[rr];
            float p = __builtin_amdgcn_exp2f(lg);
            S[t][rr] = p;
            sm4[rr] += p;
        }
    }
    #pragma unroll
    for (int rr = 0; rr < 4; ++rr) {
        sm4[rr] += __shfl_xor(sm4[rr], 1);
        sm4[rr] += __shfl_xor(sm4[rr], 2);
        sm4[rr] += __shfl_xor(sm4[rr], 4);
        sm4[rr] += __shfl_xor(sm4[rr], 8);
    }
    if (ll == 0) {
        #pragma unroll
        for (int rr = 0; rr < 4; ++rr) smR[row0 + rr] = sm4[rr];
    }

    __syncthreads();       // Vt staging visible to all; Ps overlays RhTw/Rww
                           // (strip is wave-private, so only own-wave order
                           //  matters -> in-order DS pipe suffices there)

    // ---- P -> LDS row-major (wave-private strip), B-operand-readable
    #pragma unroll
    for (int t = 0; t < 14; ++t) {
        int col = t * 16 + ll;
        #pragma unroll
        for (int rr = 0; rr < 4; ++rr)
            Ps[(lq * 4 + rr) * 232 + col] = f2bf(S[t][rr]);
    }

    // ---- O^T = V^T P^T: A = Vt (b128), B = Ps (b128), 14 MFMAs
    f4 O[2] = {zero4, zero4};
    #pragma unroll
    for (int kt = 0; kt < 7; ++kt) {
        bh8 bp = *(const bh8*)&Ps[ll * 232 + kt * 32 + lq * 8];
        #pragma unroll
        for (int mt = 0; mt < 2; ++mt) {
            int d = mt * 16 + ll;
            int s = ((d & 3) + ((d >> 3) & 3)) & 3;
            bh8 av = *(const bh8*)&Vt[d * 240 + (((kt * 4 + lq) ^ s) * 8)];
            O[mt] = __builtin_amdgcn_mfma_f32_16x16x32_bf16(av, bp, O[mt], 0, 0, 0);
        }
    }

    // ---- epilogue: O^T lanes are pixel-consecutive -> coalesced-8 stores
    int qp = m0 + ll;
    float rs = 1.0f / smR[qp];
    int pix = (r0 + (qp >> 3)) * 96 + c0 + (qp & 7);
    float* ob = out + (size_t)(b * 256 + head * 32) * NPIX;
    #pragma unroll
    for (int mt = 0; mt < 2; ++mt) {
        #pragma unroll
        for (int rr = 0; rr < 4; ++rr) {
            int d = mt * 16 + lq * 4 + rr;
            ob[(size_t)d * NPIX + pix] = O[mt][rr] * rs;
        }
    }
}

extern "C" void kernel_launch(void* const* d_in, const int* in_sizes, int n_in,
                              void* d_out, int out_size, void* d_ws, size_t ws_size,
                              hipStream_t stream) {
    const float* x    = (const float*)d_in[0];
    const float* qw   = (const float*)d_in[1];
    const float* kvw  = (const float*)d_in[2];
    const float* hrel = (const float*)d_in[3];
    const float* wrel = (const float*)d_in[4];
    float* out = (float*)d_out;

    char* ws = (char*)d_ws;
    unsigned short* xt    = (unsigned short*)ws;                 // 37,748,736 B
    unsigned short* Wb    = (unsigned short*)(ws + 37748736);    //    393,216 B
    unsigned short* relb  = (unsigned short*)(ws + 38141952);    //      4,096 B
    unsigned short* qbuf  = (unsigned short*)(ws + 38146048);    // 37,748,736 B
    unsigned short* kvbuf = (unsigned short*)(ws + 75894784);    // 75,497,472 B

    wconv_kernel<<<dim3(776), 256, 0, stream>>>(qw, kvw, hrel, wrel, Wb, relb);
    xtrans_kernel<<<dim3(72, 2, 8), 256, 0, stream>>>(x, xt);
    proj_kernel<<<dim3(72, 6, 8), 256, 0, stream>>>(xt, Wb, qbuf, kvbuf);
    attn_kernel<<<dim3(144, 64), 256, 0, stream>>>(qbuf, kvbuf, relb, out);
}

// Round 5
// 258.526 us; speedup vs baseline: 1.1678x; 1.1678x over previous
//
#include <hip/hip_runtime.h>
#include <math.h>

#define NPIX 9216        // 96*96
#define SCALE 0.17677669529663687f
#define LOG2E 1.4426950408889634f

typedef __attribute__((ext_vector_type(8))) short bh8;   // 8 x bf16 (4 VGPRs)
typedef __attribute__((ext_vector_type(4))) float f4;    // MFMA C/D

__device__ __forceinline__ unsigned short f2bf(float f) {
    unsigned u = __float_as_uint(f);
    u += 0x7fff + ((u >> 16) & 1);          // RNE
    return (unsigned short)(u >> 16);
}
__device__ __forceinline__ void gload_lds16(const void* g, void* l) {
    __builtin_amdgcn_global_load_lds(
        (const __attribute__((address_space(1))) unsigned int*)g,
        (__attribute__((address_space(3))) unsigned int*)l, 16, 0, 0);
}

// ---------------------------------------------------------------------------
// Kernel 0: W (q;kv) fp32 -> bf16 [768][256]; blocks 768+: hrel/wrel fp32 ->
// bf16 relb[2][32][32], pre-scaled by LOG2E, rows >=27 zeroed.
// ---------------------------------------------------------------------------
__global__ void wconv_kernel(const float* __restrict__ qw, const float* __restrict__ kvw,
                             const float* __restrict__ hrel, const float* __restrict__ wrel,
                             unsigned short* __restrict__ Wb,
                             unsigned short* __restrict__ relb) {
    int bid = blockIdx.x, tid = threadIdx.x;
    if (bid < 768) {
        float v = (bid < 256) ? qw[bid * 256 + tid] : kvw[(bid - 256) * 256 + tid];
        Wb[bid * 256 + tid] = f2bf(v);
    } else {
        int e = (bid - 768) * 256 + tid;      // [0, 2048)
        int half = e >> 10, r = (e >> 5) & 31, d = e & 31;
        float v = 0.0f;
        if (r < 27) v = (half ? wrel : hrel)[r * 32 + d] * LOG2E;
        relb[half * 1024 + r * 32 + d] = f2bf(v);
    }
}

// ---------------------------------------------------------------------------
// Kernel 1: x[b][256][9216] fp32 -> xt[b][9216][256] bf16 (transpose+convert)
// ---------------------------------------------------------------------------
__global__ __launch_bounds__(256) void xtrans_kernel(const float* __restrict__ x,
                                                     unsigned short* __restrict__ xt) {
    int b = blockIdx.z;
    int p0 = blockIdx.x * 128, c0 = blockIdx.y * 128;
    int tid = threadIdx.x;
    __shared__ __align__(16) unsigned short ts[128 * 136];   // [pix][ch], pitch 136
    const float* xb = x + (size_t)b * 256 * NPIX;
    #pragma unroll
    for (int it = 0; it < 16; ++it) {
        int e = it * 256 + tid;
        int ch = e >> 5, p4 = (e & 31) * 4;
        float4 v = *(const float4*)(xb + (size_t)(c0 + ch) * NPIX + p0 + p4);
        ts[(p4 + 0) * 136 + ch] = f2bf(v.x);
        ts[(p4 + 1) * 136 + ch] = f2bf(v.y);
        ts[(p4 + 2) * 136 + ch] = f2bf(v.z);
        ts[(p4 + 3) * 136 + ch] = f2bf(v.w);
    }
    __syncthreads();
    unsigned short* xtb = xt + (size_t)b * NPIX * 256;
    #pragma unroll
    for (int it = 0; it < 8; ++it) {
        int e = it * 256 + tid;
        int p = e >> 4, ck = (e & 15) * 8;
        *(int4*)(xtb + (size_t)(p0 + p) * 256 + c0 + ck) = *(const int4*)&ts[p * 136 + ck];
    }
}

// ---------------------------------------------------------------------------
// Kernel 2: projection GEMM, bf16 MFMA (unchanged from round 1).
// ---------------------------------------------------------------------------
__global__ __launch_bounds__(256) void proj_kernel(const unsigned short* __restrict__ xt,
                                                   const unsigned short* __restrict__ Wb,
                                                   unsigned short* __restrict__ qb,
                                                   unsigned short* __restrict__ kvb) {
    int flat = blockIdx.x + 72 * (blockIdx.y + 6 * blockIdx.z);   // 0..3455, x fastest
    int w = (flat & 7) * 432 + (flat >> 3);    // per-XCD contiguous slot run
    int n0 = (w % 6) * 128;                    // out-ch block (fastest within XCD)
    int m0 = ((w / 6) % 72) * 128;             // pix block
    int b  = w / 432;                          // == xcd: one batch per XCD
    int tid = threadIdx.x, lane = tid & 63, wave = tid >> 6;
    int ll = lane & 15;
    __shared__ __align__(16) char smem[34816];
    char* As = smem;             // [128 pix][64 k] bf16, rows 128 B
    char* Bs = smem + 16384;     // [128 ch ][64 k] bf16
    const unsigned short* xtb = xt + (size_t)b * NPIX * 256;

    f4 acc[4][4] = {};
    int wm = (wave & 1) * 64, wn = (wave >> 1) * 64;

    for (int k0 = 0; k0 < 256; k0 += 64) {
        __syncthreads();
        #pragma unroll
        for (int i = 0; i < 4; ++i) {
            int c = wave * 4 + i;   // chunk: 8 rows x 128B = 1 KB
            gload_lds16(xtb + (size_t)(m0 + c * 8 + (lane >> 3)) * 256 + k0 + (lane & 7) * 8,
                        As + c * 1024);
            gload_lds16(Wb + (size_t)(n0 + c * 8 + (lane >> 3)) * 256 + k0 + (lane & 7) * 8,
                        Bs + c * 1024);
        }
        __syncthreads();
        #pragma unroll
        for (int ks = 0; ks < 2; ++ks) {
            bh8 af[4], bf[4];
            #pragma unroll
            for (int i = 0; i < 4; ++i)
                af[i] = *(const bh8*)(As + (wm + i * 16 + ll) * 128 + ks * 64 + (lane >> 4) * 16);
            #pragma unroll
            for (int j = 0; j < 4; ++j)
                bf[j] = *(const bh8*)(Bs + (wn + j * 16 + ll) * 128 + ks * 64 + (lane >> 4) * 16);
            #pragma unroll
            for (int i = 0; i < 4; ++i)
                #pragma unroll
                for (int j = 0; j < 4; ++j)
                    acc[i][j] = __builtin_amdgcn_mfma_f32_16x16x32_bf16(af[i], bf[j], acc[i][j], 0, 0, 0);
        }
    }

    // ---- epilogue: acc -> LDS bf16 tile [128][136] -> coalesced int4 stores
    __syncthreads();
    unsigned short* ts = (unsigned short*)smem;
    int q4 = (lane >> 4) * 4;
    #pragma unroll
    for (int i = 0; i < 4; ++i) {
        #pragma unroll
        for (int j = 0; j < 4; ++j) {
            int ch = wn + j * 16 + ll;
            #pragma unroll
            for (int r = 0; r < 4; ++r)
                ts[(wm + i * 16 + q4 + r) * 136 + ch] = f2bf(acc[i][j][r]);
        }
    }
    __syncthreads();
    bool isQ = (n0 < 256);
    #pragma unroll
    for (int it = 0; it < 8; ++it) {
        int e = it * 256 + tid;
        int pixl = e >> 4, ck = (e & 15) * 8;
        int4 v = *(const int4*)&ts[pixl * 136 + ck];
        int pix = m0 + pixl, ch = n0 + ck;
        if (isQ) {
            int head = ch >> 5, d = ch & 31;
            *(int4*)&qb[((size_t)(b * 8 + head) * NPIX + pix) * 32 + d] = v;
        } else {
            int c = ch - 256, head = c >> 6, dv = c & 63;
            *(int4*)&kvb[((size_t)(b * 8 + head) * NPIX + pix) * 64 + dv] = v;
        }
    }
}

// ---------------------------------------------------------------------------
// Kernel 3: halo attention, round-1 dataflow at 4 blocks/CU.
//   - K STAGED in LDS (round-1; round-4's direct-K serialized at 72 VGPR).
//   - rel-MFMA moved AFTER QK so RhTw/Rww/Ps strips overlay the dead Ks
//     region (extra barrier S1b; strips are wave-private past it).
//   - Ps halved by 2-chunk PV: write P cols 0-127 -> PV kt 0-3, then
//     overwrite with cols 128-223 -> PV kt 4-6 (same-wave DS order safe).
//   - Vt pitch 240 -> 224 (28 granules; g^s stays < 28).
// LDS map (32512 B -> 4 blocks/CU):
//   [0,14336)        Vt[32][224] bf16, granule-XOR swizzled   (all phases)
//   [14336,32256)    Ks[224][40] bf16                          (phase A)
//   [14336,31744)    strips 4 x 4352 B (phase B, overlay Ks):
//       [0,2240)  RhTw[28][20] fp32   (dies at logits)
//       [2240,3712) Rww[16][23] fp32  (dies at logits)
//       [0,4352)  Ps[16][136] bf16    (overlay after logits)
//   [32256,32512)    smR[64] fp32 row-sums (wave-private rows)
// ---------------------------------------------------------------------------
__global__ __launch_bounds__(256, 4) void attn_kernel(const unsigned short* __restrict__ qbuf,
                                                      const unsigned short* __restrict__ kvbuf,
                                                      const unsigned short* __restrict__ relb,
                                                      float* __restrict__ out) {
    int flat = blockIdx.x + 144 * blockIdx.y;       // 0..9215, x fastest
    int w = (flat & 7) * 1152 + (flat >> 3);        // XCD gets 8 full bh planes
    int nbid = w % 144, bh = w / 144;
    int b = bh >> 3, head = bh & 7;
    int hb = nbid / 12, wblk = nbid % 12;
    int r0 = hb * 8, c0 = wblk * 8;
    int tid = threadIdx.x, lane = tid & 63, wave = tid >> 6;
    int ll = lane & 15, lq = lane >> 4;
    int m0 = wave * 16;

    __shared__ __align__(16) char smem[32512];
    unsigned short* Vt = (unsigned short*)smem;                 // [32][224]
    unsigned short* Ks = (unsigned short*)(smem + 14336);       // [224][40]
    char* strip = smem + 14336 + wave * 4352;
    float*          RhTw = (float*)strip;                       // [28][20]
    float*          Rww  = (float*)(strip + 2240);              // [16][23]
    unsigned short* Ps   = (unsigned short*)strip;              // [16][136] overlay
    float*          smR  = (float*)(smem + 32256);

    const unsigned short* qb  = qbuf  + (size_t)bh * NPIX * 32;
    const unsigned short* kvb = kvbuf + (size_t)bh * NPIX * 64;

    // ---- Q fragment straight from global (A-operand layout)
    int qp0 = m0 + ll;
    int pixq = (r0 + (qp0 >> 3)) * 96 + c0 + (qp0 & 7);
    bh8 aq = *(const bh8*)&qb[(size_t)pixq * 32 + lq * 8];

    // ---- stage K: 224 rows x 64 B, pad/halo-zeroed
    for (int e = tid; e < 896; e += 256) {
        int kp = e >> 2, part = e & 3;
        int a = kp >> 4, b2 = kp & 15;
        int gr = r0 + a - 3, gc = c0 + b2 - 3;
        int4 v = {0, 0, 0, 0};
        if (b2 < 14 && (unsigned)gr < 96u && (unsigned)gc < 96u)
            v = *(const int4*)&kvb[(size_t)(gr * 96 + gc) * 64 + part * 8];
        *(int4*)&Ks[kp * 40 + part * 8] = v;
    }

    // ---- stage V transposed: Vt[d][granule-swizzled kp], pair-packed b32
    #pragma unroll
    for (int it = 0; it < 2; ++it) {
        int e = it * 256 + tid;
        int part = e >> 7, kp2 = e & 127;
        if (kp2 < 112) {
            int a = kp2 >> 3, b2 = (kp2 & 7) * 2;
            int gr = r0 + a - 3, gc = c0 + b2 - 3;
            int4 lo = {0, 0, 0, 0}, hi = {0, 0, 0, 0};
            bool rok = ((kp2 & 7) < 7) && ((unsigned)gr < 96u);
            if (rok && (unsigned)gc < 96u)
                lo = *(const int4*)&kvb[(size_t)(gr * 96 + gc) * 64 + 32 + part * 8];
            if (rok && (unsigned)(gc + 1) < 96u)
                hi = *(const int4*)&kvb[(size_t)(gr * 96 + gc + 1) * 64 + 32 + part * 8];
            int g = kp2 >> 2, kb = b2 & 7;
            const unsigned* lw = (const unsigned*)&lo;
            const unsigned* hw = (const unsigned*)&hi;
            #pragma unroll
            for (int jw = 0; jw < 4; ++jw) {
                unsigned l2 = lw[jw], h2 = hw[jw];
                unsigned v0 = (l2 & 0xffffu) | (h2 << 16);
                unsigned v1 = (l2 >> 16) | (h2 & 0xffff0000u);
                int d0 = part * 8 + jw * 2;
                int s0 = (((jw * 2) & 3) + part) & 3;
                int s1 = (((jw * 2 + 1) & 3) + part) & 3;
                *(unsigned*)&Vt[d0 * 224 + ((g ^ s0) * 8) + kb] = v0;
                *(unsigned*)&Vt[(d0 + 1) * 224 + ((g ^ s1) * 8) + kb] = v1;
            }
        }
    }

    __syncthreads();                               // S1: Ks/Vt staging visible

    // ---- S = Q K^T (14 MFMAs from staged Ks)
    f4 zero4 = {0.f, 0.f, 0.f, 0.f};
    f4 S[14];
    #pragma unroll
    for (int t = 0; t < 14; ++t) {
        bh8 bk = *(const bh8*)&Ks[(t * 16 + ll) * 40 + lq * 8];
        S[t] = __builtin_amdgcn_mfma_f32_16x16x32_bf16(aq, bk, zero4, 0, 0, 0);
    }

    __syncthreads();                               // S1b: all waves done with Ks

    // ---- rel dot-products via MFMA -> wave-private strips (overlay Ks)
    #pragma unroll
    for (int t = 0; t < 2; ++t) {
        int r = t * 16 + ll;
        bh8 hbv = *(const bh8*)&relb[(size_t)r * 32 + lq * 8];
        bh8 wbv = *(const bh8*)&relb[1024 + (size_t)r * 32 + lq * 8];
        f4 ch = __builtin_amdgcn_mfma_f32_16x16x32_bf16(aq, hbv, zero4, 0, 0, 0);
        f4 cw = __builtin_amdgcn_mfma_f32_16x16x32_bf16(aq, wbv, zero4, 0, 0, 0);
        if (r < 28) *(f4*)&RhTw[r * 20 + lq * 4] = ch;
        if (r >= 6 && r < 27) {
            #pragma unroll
            for (int rr = 0; rr < 4; ++rr)
                Rww[(lq * 4 + rr) * 23 + (r - 6)] = cw[rr];
        }
    }

    // ---- logits (log2 domain), exp2 without max-subtraction, row sums
    int row0 = m0 + lq * 4;
    int h = row0 >> 3;                             // quad-uniform
    bool valid = (ll < 14);
    float rw4[4];
    #pragma unroll
    for (int rr = 0; rr < 4; ++rr) {
        int row = row0 + rr;
        rw4[rr] = valid ? Rww[(lq * 4 + rr) * 23 + 7 + ll - (row & 7)] : -INFINITY;
    }
    const float SL = SCALE * LOG2E;
    float sm4[4] = {0.f, 0.f, 0.f, 0.f};
    #pragma unroll
    for (int t = 0; t < 14; ++t) {
        f4 rh = *(const f4*)&RhTw[(13 + t - h) * 20 + lq * 4];
        #pragma unroll
        for (int rr = 0; rr < 4; ++rr) {
            float lg = S[t][rr] * SL + rh[rr] + rw4[rr];
            float p = __builtin_amdgcn_exp2f(lg);
            S[t][rr] = p;
            sm4[rr] += p;
        }
    }
    #pragma unroll
    for (int rr = 0; rr < 4; ++rr) {
        sm4[rr] += __shfl_xor(sm4[rr], 1);
        sm4[rr] += __shfl_xor(sm4[rr], 2);
        sm4[rr] += __shfl_xor(sm4[rr], 4);
        sm4[rr] += __shfl_xor(sm4[rr], 8);
    }
    if (ll == 0) {
        #pragma unroll
        for (int rr = 0; rr < 4; ++rr) smR[row0 + rr] = sm4[rr];
    }
    // no barrier: strip + smR rows are wave-private; same-wave DS ops are
    // in-order, and aliasing via the same base array pins compiler order.

    // ---- 2-chunk P->LDS + PV (Ps half-size: cols 0-127 then 128-223)
    f4 O[2] = {zero4, zero4};
    #pragma unroll
    for (int c = 0; c < 2; ++c) {
        const int nt = c ? 6 : 8;
        #pragma unroll
        for (int tl = 0; tl < 8; ++tl) {
            if (tl < nt) {
                int t = c * 8 + tl;
                int col = tl * 16 + ll;
                #pragma unroll
                for (int rr = 0; rr < 4; ++rr)
                    Ps[(lq * 4 + rr) * 136 + col] = f2bf(S[t][rr]);
            }
        }
        const int nkt = c ? 3 : 4;
        #pragma unroll
        for (int ktl = 0; ktl < 4; ++ktl) {
            if (ktl < nkt) {
                int kt = c * 4 + ktl;
                bh8 bp = *(const bh8*)&Ps[ll * 136 + ktl * 32 + lq * 8];
                #pragma unroll
                for (int mt = 0; mt < 2; ++mt) {
                    int d = mt * 16 + ll;
                    int s = ((d & 3) + ((d >> 3) & 3)) & 3;
                    bh8 av = *(const bh8*)&Vt[d * 224 + (((kt * 4 + lq) ^ s) * 8)];
                    O[mt] = __builtin_amdgcn_mfma_f32_16x16x32_bf16(av, bp, O[mt], 0, 0, 0);
                }
            }
        }
    }

    // ---- epilogue: O^T lanes are pixel-consecutive -> coalesced-8 stores
    int qp = m0 + ll;
    float rs = 1.0f / smR[qp];
    int pix = (r0 + (qp >> 3)) * 96 + c0 + (qp & 7);
    float* ob = out + (size_t)(b * 256 + head * 32) * NPIX;
    #pragma unroll
    for (int mt = 0; mt < 2; ++mt) {
        #pragma unroll
        for (int rr = 0; rr < 4; ++rr) {
            int d = mt * 16 + lq * 4 + rr;
            ob[(size_t)d * NPIX + pix] = O[mt][rr] * rs;
        }
    }
}

extern "C" void kernel_launch(void* const* d_in, const int* in_sizes, int n_in,
                              void* d_out, int out_size, void* d_ws, size_t ws_size,
                              hipStream_t stream) {
    const float* x    = (const float*)d_in[0];
    const float* qw   = (const float*)d_in[1];
    const float* kvw  = (const float*)d_in[2];
    const float* hrel = (const float*)d_in[3];
    const float* wrel = (const float*)d_in[4];
    float* out = (float*)d_out;

    char* ws = (char*)d_ws;
    unsigned short* xt    = (unsigned short*)ws;                 // 37,748,736 B
    unsigned short* Wb    = (unsigned short*)(ws + 37748736);    //    393,216 B
    unsigned short* relb  = (unsigned short*)(ws + 38141952);    //      4,096 B
    unsigned short* qbuf  = (unsigned short*)(ws + 38146048);    // 37,748,736 B
    unsigned short* kvbuf = (unsigned short*)(ws + 75894784);    // 75,497,472 B

    wconv_kernel<<<dim3(776), 256, 0, stream>>>(qw, kvw, hrel, wrel, Wb, relb);
    xtrans_kernel<<<dim3(72, 2, 8), 256, 0, stream>>>(x, xt);
    proj_kernel<<<dim3(72, 6, 8), 256, 0, stream>>>(xt, Wb, qbuf, kvbuf);
    attn_kernel<<<dim3(144, 64), 256, 0, stream>>>(qbuf, kvbuf, relb, out);
}